// Round 9
// baseline (182.046 us; speedup 1.0000x reference)
//
#include <hip/hip_runtime.h>

#define N_NODES 100000
#define N_EDGES 1600000
#define IN_F    128
#define HEADS   4
#define OUT_F   16
#define HF      64
#define NEG_SLOPE 0.2f

#define BUCK    112        // nodes per scatter bucket (= nodes per k3 block)
#define NBUCK   893        // ceil(N_NODES/112)
#define BSTRIDE 2048       // bin slots per bucket (mean 1792, +6 sigma)

// two-level bsc: 4096-edge chunks, LDS counting sort, coalesced run copy-out
#define BSC_CHUNK 4096
#define NB_BSC5 391        // ceil(E/4096)

// fused grid: 1:2 interleave (bx%3==0 -> bsc, else k1), 23 KB LDS -> 4 blocks/CU (wave cap)
#define NB_MFMA2 782       // ceil(N_NODES/128)
#define NB_FUSED5 1173     // 3*391

// k3 head-split: block bx -> xcd = bx&7 (HW round-robin), half = (bx&7)>>2,
// bucket = (bx>>3)*4 + (bx&3). XCDs 0-3 touch only zbh half 0 (6.4 MB), XCDs 4-7
// only half 1 -> per-XCD L2 compulsory zb traffic halves (102 -> 51 MB).
#define K3H_BLOCKS 1792    // 224 * 8 (covers buckets 0..895, guard >= 893)

typedef __attribute__((ext_vector_type(8))) short short8;
typedef __attribute__((ext_vector_type(4))) float f32x4;

__device__ __forceinline__ short f2bf(float f) {
    union { float f; unsigned u; } v; v.f = f;
    return (short)((v.u + 0x7FFFu + ((v.u >> 16) & 1u)) >> 16);
}

// ---------------- k_prep: zero gcur; build bf16 B-fragments (24 parallel blocks) ----------------
__global__ __launch_bounds__(256) void k_prep(const float* __restrict__ W,
                                              const float* __restrict__ attn_l,
                                              const float* __restrict__ attn_r,
                                              unsigned short* __restrict__ Wfrag,
                                              int* __restrict__ gcur) {
    const int g = blockIdx.x, t = threadIdx.x;
    if (g >= 20) {                       // blocks 20..23: zero gcur (1024 ints)
        int i = (g - 20) * 256 + t;
        if (i < 1024) gcur[i] = 0;
        return;
    }
    const int ct = g >> 2, kf = g & 3;   // fragment group: 512 elems per block
    #pragma unroll
    for (int e = 0; e < 2; ++e) {
        int off = e * 256 + t;           // 0..511 ; idx = g*512 + off = (g*64+lane)*8 + j
        int j = off & 7, lane = off >> 3;
        int n = lane & 15, qq = lane >> 4;
        int k = kf * 32 + qq * 8 + j;
        float v;
        if (ct < 4) {
            v = W[(size_t)(ct * 16 + n) * IN_F + k];
        } else if (n < 8) {
            int hh = n & 3;
            const float* at = (n < 4) ? attn_l : attn_r;
            v = 0.f;
            #pragma unroll
            for (int f = 0; f < 16; ++f)
                v += W[(size_t)(hh * 16 + f) * IN_F + k] * at[hh * 16 + f];
        } else {
            v = 0.f;
        }
        Wfrag[(size_t)g * 512 + off] = (unsigned short)f2bf(v);
    }
}

// ---------------- fused: two-level bsc (compact LDS sort + coalesced copy-out) + k1 MFMA ----------------
__global__ __launch_bounds__(512) void k_fused(const float* __restrict__ feats,
                                               const unsigned short* __restrict__ Wfrag,
                                               unsigned short* __restrict__ zbh,
                                               float* __restrict__ el,
                                               float* __restrict__ er,
                                               const int* __restrict__ src,
                                               const int* __restrict__ dst,
                                               int* __restrict__ gcur,
                                               unsigned* __restrict__ bin) {
    const int t = threadIdx.x;
    const unsigned bx = blockIdx.x;
    const unsigned q3 = bx / 3u, r3 = bx % 3u;

    if (r3 == 0u) {
        // ---------- bsc path: LDS counting sort of a 4096-edge chunk ----------
        __shared__ unsigned sortedL[BSC_CHUNK];   // 16 KiB
        __shared__ int hist[NBUCK];               // 3.5 KiB
        __shared__ int cur[NBUCK];                // 3.5 KiB

        const int bid = (int)q3;                  // 0..390
        const int start = bid * BSC_CHUNK;
        int end = start + BSC_CHUNK;
        if (end > N_EDGES) end = N_EDGES;

        for (int i = t; i < NBUCK; i += 512) hist[i] = 0;
        __syncthreads();

        // pass 1: histogram (coalesced dst read); cache (b<<7)|dl in regs
        unsigned myv[8];
        #pragma unroll
        for (int k = 0; k < 8; ++k) {
            int i = start + t + k * 512;
            if (i < end) {
                unsigned d = (unsigned)dst[i];
                unsigned b = d / BUCK;
                myv[k] = (b << 7) | (d - b * BUCK);
                atomicAdd(&hist[b], 1);
            } else myv[k] = 0xFFFFFFFFu;
        }
        __syncthreads();

        // single-wave exclusive scan of hist -> cur (893 bins, 14 per lane)
        if (t < 64) {
            int base = t * 14;
            int loc[14]; int acc = 0;
            #pragma unroll
            for (int k = 0; k < 14; ++k) {
                int idx = base + k;
                int v = (idx < NBUCK) ? hist[idx] : 0;
                loc[k] = acc; acc += v;
            }
            int x = acc;
            #pragma unroll
            for (int o = 1; o < 64; o <<= 1) {
                int y = __shfl_up(x, o);
                if (t >= o) x += y;
            }
            int excl = x - acc;
            #pragma unroll
            for (int k = 0; k < 14; ++k) {
                int idx = base + k;
                if (idx < NBUCK) cur[idx] = excl + loc[k];
            }
        }
        __syncthreads();

        // pass 2: scatter into LDS sorted by bucket (src read coalesced; no dst re-read)
        #pragma unroll
        for (int k = 0; k < 8; ++k) {
            if (myv[k] != 0xFFFFFFFFu) {
                int i = start + t + k * 512;
                unsigned b = myv[k] >> 7;
                unsigned dl = myv[k] & 127u;
                int pos = atomicAdd(&cur[b], 1);
                sortedL[pos] = (unsigned)src[i] | (dl << 17);
            }
        }
        __syncthreads();

        // copy-out: thread owns bucket(s); reserve gcur range then write the
        // run (~4.6 edges) to CONSECUTIVE global addresses.
        for (int b = t; b < NBUCK; b += 512) {
            int n = hist[b];
            if (!n) continue;
            int lo = cur[b] - n;                 // cur[b] is now the end offset
            int gb = atomicAdd(&gcur[b], n);
            unsigned* dp = bin + (size_t)b * BSTRIDE;
            for (int k2 = 0; k2 < n; ++k2) {
                int gpos = gb + k2;
                if (gpos < BSTRIDE) dp[gpos] = sortedL[lo + k2];
            }
        }
        return;
    }

    // ---------- k1 path: [z | el | er] = feats @ Bfrag via MFMA, 128 nodes per block ----------
    const int bid = (int)(q3 * 2u + (r3 - 1u));  // 0..781

    const int grp = t >> 6;          // 0..7
    const int l = t & 63;
    const int q = l >> 4, n = l & 15;

    short8 bfrag[5][4];
    #pragma unroll
    for (int ct = 0; ct < 5; ++ct)
        #pragma unroll
        for (int kf = 0; kf < 4; ++kf)
            bfrag[ct][kf] = *(const short8*)(Wfrag + (size_t)((ct * 4 + kf) * 64 + l) * 8);

    int anode = bid * 128 + grp * 16 + n;
    int aclamp = anode < N_NODES ? anode : 0;
    const float* arow = feats + (size_t)aclamp * IN_F + q * 8;

    f32x4 acc[5];
    #pragma unroll
    for (int ct = 0; ct < 5; ++ct) acc[ct] = (f32x4){0.f, 0.f, 0.f, 0.f};

    #pragma unroll
    for (int kf = 0; kf < 4; ++kf) {
        float4 x = *(const float4*)(arow + kf * 32);
        float4 y = *(const float4*)(arow + kf * 32 + 4);
        short8 a;
        a[0] = f2bf(x.x); a[1] = f2bf(x.y); a[2] = f2bf(x.z); a[3] = f2bf(x.w);
        a[4] = f2bf(y.x); a[5] = f2bf(y.y); a[6] = f2bf(y.z); a[7] = f2bf(y.w);
        #pragma unroll
        for (int ct = 0; ct < 5; ++ct)
            acc[ct] = __builtin_amdgcn_mfma_f32_16x16x32_bf16(a, bfrag[ct][kf], acc[ct], 0, 0, 0);
    }

    #pragma unroll
    for (int reg = 0; reg < 4; ++reg) {
        int onode = bid * 128 + grp * 16 + q * 4 + reg;
        if (onode >= N_NODES) continue;
        // head-pair-major z: zbh[(half*N + node)*32 + (ct&1)*16 + n]
        #pragma unroll
        for (int ct = 0; ct < 4; ++ct)
            zbh[((size_t)(ct >> 1) * N_NODES + onode) * 32 + (ct & 1) * 16 + n] =
                (unsigned short)f2bf(acc[ct][reg]);
        float v4 = acc[4][reg];
        if (n < 4)       el[onode * HEADS + n] = v4;
        else if (n < 8)  er[onode * HEADS + (n - 4)] = v4;
    }
}

// ---------------- k3: LDS count-sort + HALF aggregation (2 heads) per block ----------------
// Two blocks per bucket; half chosen from bx&7 so each XCD only touches one zbh half.
__global__ __launch_bounds__(512) void k3_sort(const unsigned* __restrict__ bin,
                                               const int* __restrict__ gcur,
                                               const float* __restrict__ el,
                                               const float* __restrict__ er,
                                               const unsigned short* __restrict__ zbh,
                                               const float* __restrict__ bias,
                                               float* __restrict__ out) {
    __shared__ unsigned raw[BSTRIDE];      // 8 KiB: staged bin bucket
    __shared__ unsigned sorted[BSTRIDE];   // 8 KiB: src sorted by dst-local
    __shared__ int hist[BUCK];
    __shared__ int noff[BUCK + 1];
    __shared__ int cur[BUCK];
    __shared__ int s[128];
    __shared__ float er_s[BUCK * 2];       // 2 heads of this half

    const int t = threadIdx.x;
    const unsigned bx = blockIdx.x;
    const int half = (int)((bx & 7u) >> 2);
    const int B = (int)((bx >> 3) * 4u + (bx & 3u));
    if (B >= NBUCK) return;
    const int nodebase = B * BUCK;
    const unsigned* mybin = bin + (size_t)B * BSTRIDE;
    int cnt = gcur[B];
    if (cnt > BSTRIDE) cnt = BSTRIDE;

    if (t < BUCK) hist[t] = 0;
    if (t < BUCK * 2) {                    // er for heads {2*half, 2*half+1}
        int node = nodebase + (t >> 1);
        er_s[t] = (node < N_NODES) ? er[node * HEADS + half * 2 + (t & 1)] : 0.f;
    }
    for (int i = t; i < cnt; i += 512) raw[i] = mybin[i];
    __syncthreads();

    // pass 1: histogram (every edge is in range for a full bucket)
    for (int i = t; i < cnt; i += 512)
        atomicAdd(&hist[raw[i] >> 17], 1);
    __syncthreads();

    // exclusive scan over 112 bins (128-wide)
    if (t < 128) s[t] = (t < BUCK) ? hist[t] : 0;
    __syncthreads();
    for (int o = 1; o < 128; o <<= 1) {
        int x = (t < 128 && t >= o) ? s[t - o] : 0;
        __syncthreads();
        if (t < 128) s[t] += x;
        __syncthreads();
    }
    if (t < BUCK) {
        int excl = s[t] - hist[t];
        noff[t] = excl;
        cur[t] = excl;
    }
    if (t == 0) noff[BUCK] = s[BUCK - 1];
    __syncthreads();

    // pass 2: scatter src by dst-local
    for (int i = t; i < cnt; i += 512) {
        unsigned p = raw[i];
        int pos = atomicAdd(&cur[p >> 17], 1);
        sorted[pos] = p & 0x1FFFF;
    }
    __syncthreads();

    // aggregation (32 channels): lane = j*4 + c4; node-quad per wave:
    // sel = j>>2 picks node 0..3, jj = j&3 edge slot; butterfly masks 4,8.
    const int wave = t >> 6, lane = t & 63;
    const int j = lane >> 2;        // 0..15
    const int c4 = lane & 3;        // channel octet within half
    const int hl = c4 >> 1;         // local head 0/1
    const int jj = j & 3;
    const int sel = j >> 2;         // 0..3

    const unsigned short* zhalf = zbh + (size_t)half * N_NODES * 32;
    const int hglob = half * 2 + hl;

    for (int p = wave; p < BUCK / 4; p += 8) {     // 28 quads
        const int nl = p * 4 + sel;
        const int node = nodebase + nl;
        const int nlo = noff[nl], nhi = noff[nl + 1];
        const float er_d = er_s[nl * 2 + hl];

        float4 A0 = make_float4(0.f, 0.f, 0.f, 0.f);
        float4 A1 = make_float4(0.f, 0.f, 0.f, 0.f);
        float den = 0.f;
        for (int i = nlo + jj; i < nhi; i += 4) {
            int sN = (int)sorted[i];
            float x = el[sN * HEADS + hglob] + er_d;
            x = x > 0.f ? x : NEG_SLOPE * x;
            float ex = __expf(x);
            den += ex;
            uint4 v = *(const uint4*)(zhalf + (size_t)sN * 32 + c4 * 8);
            A0.x += ex * __uint_as_float(v.x << 16);
            A0.y += ex * __uint_as_float(v.x & 0xFFFF0000u);
            A0.z += ex * __uint_as_float(v.y << 16);
            A0.w += ex * __uint_as_float(v.y & 0xFFFF0000u);
            A1.x += ex * __uint_as_float(v.z << 16);
            A1.y += ex * __uint_as_float(v.z & 0xFFFF0000u);
            A1.z += ex * __uint_as_float(v.w << 16);
            A1.w += ex * __uint_as_float(v.w & 0xFFFF0000u);
        }
        // 2-level butterfly over jj (lane bits 2-3): masks 4, 8
        #pragma unroll
        for (int m = 4; m <= 8; m <<= 1) {
            A0.x += __shfl_xor(A0.x, m); A0.y += __shfl_xor(A0.y, m);
            A0.z += __shfl_xor(A0.z, m); A0.w += __shfl_xor(A0.w, m);
            A1.x += __shfl_xor(A1.x, m); A1.y += __shfl_xor(A1.y, m);
            A1.z += __shfl_xor(A1.z, m); A1.w += __shfl_xor(A1.w, m);
            den  += __shfl_xor(den,  m);
        }
        if (jj == 0 && node < N_NODES) {
            float4 b0 = *(const float4*)(bias + half * 32 + c4 * 8);
            float4 b1 = *(const float4*)(bias + half * 32 + c4 * 8 + 4);
            if (den > 0.f) {
                float inv = 1.f / den;
                b0.x += A0.x * inv; b0.y += A0.y * inv;
                b0.z += A0.z * inv; b0.w += A0.w * inv;
                b1.x += A1.x * inv; b1.y += A1.y * inv;
                b1.z += A1.z * inv; b1.w += A1.w * inv;
            }
            *(float4*)(out + (size_t)node * HF + half * 32 + c4 * 8) = b0;
            *(float4*)(out + (size_t)node * HF + half * 32 + c4 * 8 + 4) = b1;
        }
    }
}

extern "C" void kernel_launch(void* const* d_in, const int* in_sizes, int n_in,
                              void* d_out, int out_size, void* d_ws, size_t ws_size,
                              hipStream_t stream) {
    const float* feats  = (const float*)d_in[0];
    const float* W      = (const float*)d_in[1];
    const float* attn_l = (const float*)d_in[2];
    const float* attn_r = (const float*)d_in[3];
    const float* bias   = (const float*)d_in[4];
    const int*   src    = (const int*)d_in[5];
    const int*   dst    = (const int*)d_in[6];
    float* out = (float*)d_out;

    char* ws = (char*)d_ws;
    unsigned short* zbh = (unsigned short*)ws; ws += (size_t)N_NODES * HF * 2;
    float* el    = (float*)ws;                 ws += N_NODES * HEADS * 4;
    float* er    = (float*)ws;                 ws += N_NODES * HEADS * 4;
    unsigned short* Wfrag = (unsigned short*)ws; ws += 20 * 64 * 8 * 2;
    int*   gcur  = (int*)ws;                   ws += 1024 * 4;
    unsigned* bin = (unsigned*)ws;             ws += (size_t)NBUCK * BSTRIDE * 4;

    k_prep  <<<24,         256,  0, stream>>>(W, attn_l, attn_r, Wfrag, gcur);
    k_fused <<<NB_FUSED5,  512,  0, stream>>>(feats, Wfrag, zbh, el, er, src, dst, gcur, bin);
    k3_sort <<<K3H_BLOCKS, 512,  0, stream>>>(bin, gcur, el, er, zbh, bias, out);
}

// Round 10
// 165.611 us; speedup vs baseline: 1.0992x; 1.0992x over previous
//
#include <hip/hip_runtime.h>

#define N_NODES 100000
#define N_EDGES 1600000
#define IN_F    128
#define HEADS   4
#define OUT_F   16
#define HF      64
#define NEG_SLOPE 0.2f

#define BUCK    112        // nodes per scatter bucket (= nodes per k3 block)
#define NBUCK   893        // ceil(N_NODES/112)
#define BSTRIDE 2048       // bin slots per bucket (mean 1792, +6 sigma)

// two-level bsc: 4096-edge chunks, LDS counting sort, coalesced run copy-out
#define BSC_CHUNK 4096
#define NB_BSC5 391        // ceil(E/4096)

// fused grid: 1:2 interleave (bx%3==0 -> bsc, else k1), 23 KB LDS -> 4 blocks/CU (wave cap)
#define NB_MFMA2 782       // ceil(N_NODES/128)
#define NB_FUSED5 1173     // 3*391

typedef __attribute__((ext_vector_type(8))) short short8;
typedef __attribute__((ext_vector_type(4))) float f32x4;

__device__ __forceinline__ short f2bf(float f) {
    union { float f; unsigned u; } v; v.f = f;
    return (short)((v.u + 0x7FFFu + ((v.u >> 16) & 1u)) >> 16);
}

// ---------------- k_prep: zero gcur; build bf16 B-fragments (24 parallel blocks) ----------------
__global__ __launch_bounds__(256) void k_prep(const float* __restrict__ W,
                                              const float* __restrict__ attn_l,
                                              const float* __restrict__ attn_r,
                                              unsigned short* __restrict__ Wfrag,
                                              int* __restrict__ gcur) {
    const int g = blockIdx.x, t = threadIdx.x;
    if (g >= 20) {                       // blocks 20..23: zero gcur (1024 ints)
        int i = (g - 20) * 256 + t;
        if (i < 1024) gcur[i] = 0;
        return;
    }
    const int ct = g >> 2, kf = g & 3;   // fragment group: 512 elems per block
    #pragma unroll
    for (int e = 0; e < 2; ++e) {
        int off = e * 256 + t;           // 0..511 ; idx = g*512 + off = (g*64+lane)*8 + j
        int j = off & 7, lane = off >> 3;
        int n = lane & 15, qq = lane >> 4;
        int k = kf * 32 + qq * 8 + j;
        float v;
        if (ct < 4) {
            v = W[(size_t)(ct * 16 + n) * IN_F + k];
        } else if (n < 8) {
            int hh = n & 3;
            const float* at = (n < 4) ? attn_l : attn_r;
            v = 0.f;
            #pragma unroll
            for (int f = 0; f < 16; ++f)
                v += W[(size_t)(hh * 16 + f) * IN_F + k] * at[hh * 16 + f];
        } else {
            v = 0.f;
        }
        Wfrag[(size_t)g * 512 + off] = (unsigned short)f2bf(v);
    }
}

// ---------------- fused: two-level bsc (compact LDS sort + coalesced copy-out) + k1 MFMA ----------------
__global__ __launch_bounds__(512) void k_fused(const float* __restrict__ feats,
                                               const unsigned short* __restrict__ Wfrag,
                                               unsigned short* __restrict__ zb,
                                               float* __restrict__ el,
                                               float* __restrict__ er,
                                               const int* __restrict__ src,
                                               const int* __restrict__ dst,
                                               int* __restrict__ gcur,
                                               unsigned* __restrict__ bin) {
    const int t = threadIdx.x;
    const unsigned bx = blockIdx.x;
    const unsigned q3 = bx / 3u, r3 = bx % 3u;

    if (r3 == 0u) {
        // ---------- bsc path: LDS counting sort of a 4096-edge chunk ----------
        __shared__ unsigned sortedL[BSC_CHUNK];   // 16 KiB
        __shared__ int hist[NBUCK];               // 3.5 KiB
        __shared__ int cur[NBUCK];                // 3.5 KiB

        const int bid = (int)q3;                  // 0..390
        const int start = bid * BSC_CHUNK;
        int end = start + BSC_CHUNK;
        if (end > N_EDGES) end = N_EDGES;

        for (int i = t; i < NBUCK; i += 512) hist[i] = 0;
        __syncthreads();

        // pass 1: histogram (coalesced dst read); cache (b<<7)|dl in regs
        unsigned myv[8];
        #pragma unroll
        for (int k = 0; k < 8; ++k) {
            int i = start + t + k * 512;
            if (i < end) {
                unsigned d = (unsigned)dst[i];
                unsigned b = d / BUCK;
                myv[k] = (b << 7) | (d - b * BUCK);
                atomicAdd(&hist[b], 1);
            } else myv[k] = 0xFFFFFFFFu;
        }
        __syncthreads();

        // single-wave exclusive scan of hist -> cur (893 bins, 14 per lane)
        if (t < 64) {
            int base = t * 14;
            int loc[14]; int acc = 0;
            #pragma unroll
            for (int k = 0; k < 14; ++k) {
                int idx = base + k;
                int v = (idx < NBUCK) ? hist[idx] : 0;
                loc[k] = acc; acc += v;
            }
            int x = acc;
            #pragma unroll
            for (int o = 1; o < 64; o <<= 1) {
                int y = __shfl_up(x, o);
                if (t >= o) x += y;
            }
            int excl = x - acc;
            #pragma unroll
            for (int k = 0; k < 14; ++k) {
                int idx = base + k;
                if (idx < NBUCK) cur[idx] = excl + loc[k];
            }
        }
        __syncthreads();

        // pass 2: scatter into LDS sorted by bucket (src read coalesced; no dst re-read)
        #pragma unroll
        for (int k = 0; k < 8; ++k) {
            if (myv[k] != 0xFFFFFFFFu) {
                int i = start + t + k * 512;
                unsigned b = myv[k] >> 7;
                unsigned dl = myv[k] & 127u;
                int pos = atomicAdd(&cur[b], 1);
                sortedL[pos] = (unsigned)src[i] | (dl << 17);
            }
        }
        __syncthreads();

        // copy-out: thread owns bucket(s); reserve gcur range then write the
        // run (~4.6 edges) to CONSECUTIVE global addresses.
        for (int b = t; b < NBUCK; b += 512) {
            int n = hist[b];
            if (!n) continue;
            int lo = cur[b] - n;                 // cur[b] is now the end offset
            int gb = atomicAdd(&gcur[b], n);
            unsigned* dp = bin + (size_t)b * BSTRIDE;
            for (int k2 = 0; k2 < n; ++k2) {
                int gpos = gb + k2;
                if (gpos < BSTRIDE) dp[gpos] = sortedL[lo + k2];
            }
        }
        return;
    }

    // ---------- k1 path: [z | el | er] = feats @ Bfrag via MFMA, 128 nodes per block ----------
    const int bid = (int)(q3 * 2u + (r3 - 1u));  // 0..781

    const int grp = t >> 6;          // 0..7
    const int l = t & 63;
    const int q = l >> 4, n = l & 15;

    short8 bfrag[5][4];
    #pragma unroll
    for (int ct = 0; ct < 5; ++ct)
        #pragma unroll
        for (int kf = 0; kf < 4; ++kf)
            bfrag[ct][kf] = *(const short8*)(Wfrag + (size_t)((ct * 4 + kf) * 64 + l) * 8);

    int anode = bid * 128 + grp * 16 + n;
    int aclamp = anode < N_NODES ? anode : 0;
    const float* arow = feats + (size_t)aclamp * IN_F + q * 8;

    f32x4 acc[5];
    #pragma unroll
    for (int ct = 0; ct < 5; ++ct) acc[ct] = (f32x4){0.f, 0.f, 0.f, 0.f};

    #pragma unroll
    for (int kf = 0; kf < 4; ++kf) {
        float4 x = *(const float4*)(arow + kf * 32);
        float4 y = *(const float4*)(arow + kf * 32 + 4);
        short8 a;
        a[0] = f2bf(x.x); a[1] = f2bf(x.y); a[2] = f2bf(x.z); a[3] = f2bf(x.w);
        a[4] = f2bf(y.x); a[5] = f2bf(y.y); a[6] = f2bf(y.z); a[7] = f2bf(y.w);
        #pragma unroll
        for (int ct = 0; ct < 5; ++ct)
            acc[ct] = __builtin_amdgcn_mfma_f32_16x16x32_bf16(a, bfrag[ct][kf], acc[ct], 0, 0, 0);
    }

    #pragma unroll
    for (int reg = 0; reg < 4; ++reg) {
        int onode = bid * 128 + grp * 16 + q * 4 + reg;
        if (onode >= N_NODES) continue;
        #pragma unroll
        for (int ct = 0; ct < 4; ++ct)
            zb[(size_t)onode * HF + ct * 16 + n] = (unsigned short)f2bf(acc[ct][reg]);
        float v4 = acc[4][reg];
        if (n < 4)       el[onode * HEADS + n] = v4;
        else if (n < 8)  er[onode * HEADS + (n - 4)] = v4;
    }
}

// ---------------- fused LDS count-sort + aggregation: one 512-thread block per FULL bucket ----------------
// Round-7 structure with two micro-cuts: (a) staging fused with histogram via uint4
// loads (one global pass over bin), (b) single-wave shfl scan (no multi-barrier scan).
__global__ __launch_bounds__(512) void k3_sort(const unsigned* __restrict__ bin,
                                               const int* __restrict__ gcur,
                                               const float* __restrict__ el,
                                               const float* __restrict__ er,
                                               const unsigned short* __restrict__ zb,
                                               const float* __restrict__ bias,
                                               float* __restrict__ out) {
    __shared__ unsigned raw[BSTRIDE];      // 8 KiB: staged bin bucket
    __shared__ unsigned sorted[BSTRIDE];   // 8 KiB: src sorted by dst-local
    __shared__ int hist[BUCK];
    __shared__ int noff[BUCK + 1];
    __shared__ int cur[BUCK];
    __shared__ float er_s[BUCK * HEADS];   // 1.75 KiB

    const int t = threadIdx.x;
    const int B = blockIdx.x;
    const int nodebase = B * BUCK;
    const unsigned* mybin = bin + (size_t)B * BSTRIDE;
    int cnt = gcur[B];
    if (cnt > BSTRIDE) cnt = BSTRIDE;

    if (t < BUCK) hist[t] = 0;
    if (t < BUCK * HEADS) {                // 448 < 512
        int g = nodebase * HEADS + t;
        er_s[t] = (g < N_NODES * HEADS) ? er[g] : 0.f;
    }
    __syncthreads();

    // fused stage + histogram: one vectorized global pass over this bucket's bin
    for (int i = t * 4; i < cnt; i += 2048) {          // i <= 2044, reads within BSTRIDE
        uint4 v = *(const uint4*)(mybin + i);
        *(uint4*)(raw + i) = v;
        atomicAdd(&hist[v.x >> 17], 1);
        if (i + 1 < cnt) atomicAdd(&hist[v.y >> 17], 1);
        if (i + 2 < cnt) atomicAdd(&hist[v.z >> 17], 1);
        if (i + 3 < cnt) atomicAdd(&hist[v.w >> 17], 1);
    }
    __syncthreads();

    // single-wave exclusive scan over 112 bins (2 per lane)
    if (t < 64) {
        int h0 = hist[t * 2], h1 = hist[t * 2 + 1];
        int acc = h0 + h1;
        int x = acc;
        #pragma unroll
        for (int o = 1; o < 64; o <<= 1) {
            int y = __shfl_up(x, o);
            if (t >= o) x += y;
        }
        int excl = x - acc;
        noff[t * 2] = excl;       cur[t * 2] = excl;
        noff[t * 2 + 1] = excl + h0; cur[t * 2 + 1] = excl + h0;
        if (t == 63) noff[BUCK] = x;
    }
    __syncthreads();

    // scatter src by dst-local (pos < cnt <= BSTRIDE always)
    for (int i = t; i < cnt; i += 512) {
        unsigned p = raw[i];
        int pos = atomicAdd(&cur[p >> 17], 1);
        sorted[pos] = p & 0x1FFFF;
    }
    __syncthreads();

    // aggregation: lane = j*8 + c; node-pair per wave: sel = j>>2 picks A/B, jj = j&3 edge slot
    const int wave = t >> 6, lane = t & 63;
    const int j = lane >> 3;
    const int c = lane & 7;
    const int h = c >> 1;
    const int jj = j & 3;
    const int sel = j >> 2;

    for (int p = wave; p < BUCK / 2; p += 8) {
        const int nl = p * 2 + sel;
        const int node = nodebase + nl;
        const int nlo = noff[nl], nhi = noff[nl + 1];
        const float er_d = er_s[nl * HEADS + h];

        float4 A0 = make_float4(0.f, 0.f, 0.f, 0.f);
        float4 A1 = make_float4(0.f, 0.f, 0.f, 0.f);
        float den = 0.f;
        for (int i = nlo + jj; i < nhi; i += 4) {
            int sN = (int)sorted[i];
            float x = el[sN * HEADS + h] + er_d;
            x = x > 0.f ? x : NEG_SLOPE * x;
            float ex = __expf(x);
            den += ex;
            uint4 v = *(const uint4*)(zb + (size_t)sN * HF + c * 8);
            A0.x += ex * __uint_as_float(v.x << 16);
            A0.y += ex * __uint_as_float(v.x & 0xFFFF0000u);
            A0.z += ex * __uint_as_float(v.y << 16);
            A0.w += ex * __uint_as_float(v.y & 0xFFFF0000u);
            A1.x += ex * __uint_as_float(v.z << 16);
            A1.y += ex * __uint_as_float(v.z & 0xFFFF0000u);
            A1.z += ex * __uint_as_float(v.w << 16);
            A1.w += ex * __uint_as_float(v.w & 0xFFFF0000u);
        }
        // 2-level butterfly over jj (lane bits 3-4): masks 8, 16
        #pragma unroll
        for (int m = 8; m <= 16; m <<= 1) {
            A0.x += __shfl_xor(A0.x, m); A0.y += __shfl_xor(A0.y, m);
            A0.z += __shfl_xor(A0.z, m); A0.w += __shfl_xor(A0.w, m);
            A1.x += __shfl_xor(A1.x, m); A1.y += __shfl_xor(A1.y, m);
            A1.z += __shfl_xor(A1.z, m); A1.w += __shfl_xor(A1.w, m);
            den  += __shfl_xor(den,  m);
        }
        if (jj == 0 && node < N_NODES) {
            float4 b0 = *(const float4*)(bias + c * 8);
            float4 b1 = *(const float4*)(bias + c * 8 + 4);
            if (den > 0.f) {
                float inv = 1.f / den;
                b0.x += A0.x * inv; b0.y += A0.y * inv;
                b0.z += A0.z * inv; b0.w += A0.w * inv;
                b1.x += A1.x * inv; b1.y += A1.y * inv;
                b1.z += A1.z * inv; b1.w += A1.w * inv;
            }
            *(float4*)(out + (size_t)node * HF + c * 8) = b0;
            *(float4*)(out + (size_t)node * HF + c * 8 + 4) = b1;
        }
    }
}

extern "C" void kernel_launch(void* const* d_in, const int* in_sizes, int n_in,
                              void* d_out, int out_size, void* d_ws, size_t ws_size,
                              hipStream_t stream) {
    const float* feats  = (const float*)d_in[0];
    const float* W      = (const float*)d_in[1];
    const float* attn_l = (const float*)d_in[2];
    const float* attn_r = (const float*)d_in[3];
    const float* bias   = (const float*)d_in[4];
    const int*   src    = (const int*)d_in[5];
    const int*   dst    = (const int*)d_in[6];
    float* out = (float*)d_out;

    char* ws = (char*)d_ws;
    unsigned short* zb = (unsigned short*)ws;  ws += (size_t)N_NODES * HF * 2;
    float* el    = (float*)ws;                 ws += N_NODES * HEADS * 4;
    float* er    = (float*)ws;                 ws += N_NODES * HEADS * 4;
    unsigned short* Wfrag = (unsigned short*)ws; ws += 20 * 64 * 8 * 2;
    int*   gcur  = (int*)ws;                   ws += 1024 * 4;
    unsigned* bin = (unsigned*)ws;             ws += (size_t)NBUCK * BSTRIDE * 4;

    k_prep  <<<24,         256,  0, stream>>>(W, attn_l, attn_r, Wfrag, gcur);
    k_fused <<<NB_FUSED5,  512,  0, stream>>>(feats, Wfrag, zb, el, er, src, dst, gcur, bin);
    k3_sort <<<NBUCK,      512,  0, stream>>>(bin, gcur, el, er, zb, bias, out);
}

// Round 11
// 164.262 us; speedup vs baseline: 1.1083x; 1.0082x over previous
//
#include <hip/hip_runtime.h>

#define N_NODES 100000
#define N_EDGES 1600000
#define IN_F    128
#define HEADS   4
#define OUT_F   16
#define HF      64
#define NEG_SLOPE 0.2f

#define BUCK    112        // nodes per scatter bucket (= nodes per k3 block)
#define NBUCK   893        // ceil(N_NODES/112)
#define BSTRIDE 2048       // bin slots per bucket (mean 1792, +6 sigma)

// two-level bsc: 4096-edge chunks, LDS counting sort, coalesced run copy-out
#define BSC_CHUNK 4096
#define NB_BSC5 391        // ceil(E/4096)

// fused grid: 1:2 interleave (bx%3==0 -> bsc, else k1), 23 KB LDS -> 4 blocks/CU (wave cap)
#define NB_MFMA2 782       // ceil(N_NODES/128)
#define NB_FUSED5 1173     // 3*391

typedef __attribute__((ext_vector_type(8))) short short8;
typedef __attribute__((ext_vector_type(4))) float f32x4;

__device__ __forceinline__ short f2bf(float f) {
    union { float f; unsigned u; } v; v.f = f;
    return (short)((v.u + 0x7FFFu + ((v.u >> 16) & 1u)) >> 16);
}

// ---------------- k_prep: zero gcur; build bf16 B-fragments (24 parallel blocks) ----------------
__global__ __launch_bounds__(256) void k_prep(const float* __restrict__ W,
                                              const float* __restrict__ attn_l,
                                              const float* __restrict__ attn_r,
                                              unsigned short* __restrict__ Wfrag,
                                              int* __restrict__ gcur) {
    const int g = blockIdx.x, t = threadIdx.x;
    if (g >= 20) {                       // blocks 20..23: zero gcur (1024 ints)
        int i = (g - 20) * 256 + t;
        if (i < 1024) gcur[i] = 0;
        return;
    }
    const int ct = g >> 2, kf = g & 3;   // fragment group: 512 elems per block
    #pragma unroll
    for (int e = 0; e < 2; ++e) {
        int off = e * 256 + t;           // 0..511 ; idx = g*512 + off = (g*64+lane)*8 + j
        int j = off & 7, lane = off >> 3;
        int n = lane & 15, qq = lane >> 4;
        int k = kf * 32 + qq * 8 + j;
        float v;
        if (ct < 4) {
            v = W[(size_t)(ct * 16 + n) * IN_F + k];
        } else if (n < 8) {
            int hh = n & 3;
            const float* at = (n < 4) ? attn_l : attn_r;
            v = 0.f;
            #pragma unroll
            for (int f = 0; f < 16; ++f)
                v += W[(size_t)(hh * 16 + f) * IN_F + k] * at[hh * 16 + f];
        } else {
            v = 0.f;
        }
        Wfrag[(size_t)g * 512 + off] = (unsigned short)f2bf(v);
    }
}

// ---------------- fused: two-level bsc (compact LDS sort + coalesced copy-out) + k1 MFMA ----------------
__global__ __launch_bounds__(512) void k_fused(const float* __restrict__ feats,
                                               const unsigned short* __restrict__ Wfrag,
                                               unsigned short* __restrict__ zb,
                                               float* __restrict__ el,
                                               float* __restrict__ er,
                                               const int* __restrict__ src,
                                               const int* __restrict__ dst,
                                               int* __restrict__ gcur,
                                               unsigned* __restrict__ bin) {
    const int t = threadIdx.x;
    const unsigned bx = blockIdx.x;
    const unsigned q3 = bx / 3u, r3 = bx % 3u;

    if (r3 == 0u) {
        // ---------- bsc path: LDS counting sort of a 4096-edge chunk ----------
        __shared__ unsigned sortedL[BSC_CHUNK];   // 16 KiB
        __shared__ int hist[NBUCK];               // 3.5 KiB
        __shared__ int cur[NBUCK];                // 3.5 KiB

        const int bid = (int)q3;                  // 0..390
        const int start = bid * BSC_CHUNK;
        int end = start + BSC_CHUNK;
        if (end > N_EDGES) end = N_EDGES;

        for (int i = t; i < NBUCK; i += 512) hist[i] = 0;
        __syncthreads();

        // pass 1: histogram (coalesced dst read); cache (b<<7)|dl in regs
        unsigned myv[8];
        #pragma unroll
        for (int k = 0; k < 8; ++k) {
            int i = start + t + k * 512;
            if (i < end) {
                unsigned d = (unsigned)dst[i];
                unsigned b = d / BUCK;
                myv[k] = (b << 7) | (d - b * BUCK);
                atomicAdd(&hist[b], 1);
            } else myv[k] = 0xFFFFFFFFu;
        }
        __syncthreads();

        // single-wave exclusive scan of hist -> cur (893 bins, 14 per lane)
        if (t < 64) {
            int base = t * 14;
            int loc[14]; int acc = 0;
            #pragma unroll
            for (int k = 0; k < 14; ++k) {
                int idx = base + k;
                int v = (idx < NBUCK) ? hist[idx] : 0;
                loc[k] = acc; acc += v;
            }
            int x = acc;
            #pragma unroll
            for (int o = 1; o < 64; o <<= 1) {
                int y = __shfl_up(x, o);
                if (t >= o) x += y;
            }
            int excl = x - acc;
            #pragma unroll
            for (int k = 0; k < 14; ++k) {
                int idx = base + k;
                if (idx < NBUCK) cur[idx] = excl + loc[k];
            }
        }
        __syncthreads();

        // pass 2: scatter into LDS sorted by bucket (src read coalesced; no dst re-read)
        #pragma unroll
        for (int k = 0; k < 8; ++k) {
            if (myv[k] != 0xFFFFFFFFu) {
                int i = start + t + k * 512;
                unsigned b = myv[k] >> 7;
                unsigned dl = myv[k] & 127u;
                int pos = atomicAdd(&cur[b], 1);
                sortedL[pos] = (unsigned)src[i] | (dl << 17);
            }
        }
        __syncthreads();

        // copy-out: thread owns bucket(s); reserve gcur range then write the
        // run (~4.6 edges) to CONSECUTIVE global addresses.
        for (int b = t; b < NBUCK; b += 512) {
            int n = hist[b];
            if (!n) continue;
            int lo = cur[b] - n;                 // cur[b] is now the end offset
            int gb = atomicAdd(&gcur[b], n);
            unsigned* dp = bin + (size_t)b * BSTRIDE;
            for (int k2 = 0; k2 < n; ++k2) {
                int gpos = gb + k2;
                if (gpos < BSTRIDE) dp[gpos] = sortedL[lo + k2];
            }
        }
        return;
    }

    // ---------- k1 path: [z | el | er] = feats @ Bfrag via MFMA, 128 nodes per block ----------
    const int bid = (int)(q3 * 2u + (r3 - 1u));  // 0..781

    const int grp = t >> 6;          // 0..7
    const int l = t & 63;
    const int q = l >> 4, n = l & 15;

    short8 bfrag[5][4];
    #pragma unroll
    for (int ct = 0; ct < 5; ++ct)
        #pragma unroll
        for (int kf = 0; kf < 4; ++kf)
            bfrag[ct][kf] = *(const short8*)(Wfrag + (size_t)((ct * 4 + kf) * 64 + l) * 8);

    int anode = bid * 128 + grp * 16 + n;
    int aclamp = anode < N_NODES ? anode : 0;
    const float* arow = feats + (size_t)aclamp * IN_F + q * 8;

    f32x4 acc[5];
    #pragma unroll
    for (int ct = 0; ct < 5; ++ct) acc[ct] = (f32x4){0.f, 0.f, 0.f, 0.f};

    #pragma unroll
    for (int kf = 0; kf < 4; ++kf) {
        float4 x = *(const float4*)(arow + kf * 32);
        float4 y = *(const float4*)(arow + kf * 32 + 4);
        short8 a;
        a[0] = f2bf(x.x); a[1] = f2bf(x.y); a[2] = f2bf(x.z); a[3] = f2bf(x.w);
        a[4] = f2bf(y.x); a[5] = f2bf(y.y); a[6] = f2bf(y.z); a[7] = f2bf(y.w);
        #pragma unroll
        for (int ct = 0; ct < 5; ++ct)
            acc[ct] = __builtin_amdgcn_mfma_f32_16x16x32_bf16(a, bfrag[ct][kf], acc[ct], 0, 0, 0);
    }

    #pragma unroll
    for (int reg = 0; reg < 4; ++reg) {
        int onode = bid * 128 + grp * 16 + q * 4 + reg;
        if (onode >= N_NODES) continue;
        #pragma unroll
        for (int ct = 0; ct < 4; ++ct)
            zb[(size_t)onode * HF + ct * 16 + n] = (unsigned short)f2bf(acc[ct][reg]);
        float v4 = acc[4][reg];
        if (n < 4)       el[onode * HEADS + n] = v4;
        else if (n < 8)  er[onode * HEADS + (n - 4)] = v4;
    }
}

// ---------------- fused LDS count-sort + aggregation: one 512-thread block per FULL bucket ----------------
// Exp-hoist into the scatter pass: per edge, gather el (float4) and precompute
// exp(leaky(el+er)) for all 4 heads as fp16 in exs[] (16 KB LDS). The block is
// wave-capped at 4/CU, so LDS 20->36 KB costs NO occupancy. Agg inner loop is
// then pure LDS + zb gather + FMA.
__global__ __launch_bounds__(512) void k3_sort(const unsigned* __restrict__ bin,
                                               const int* __restrict__ gcur,
                                               const float* __restrict__ el,
                                               const float* __restrict__ er,
                                               const unsigned short* __restrict__ zb,
                                               const float* __restrict__ bias,
                                               float* __restrict__ out) {
    __shared__ unsigned raw[BSTRIDE];                      // 8 KiB
    __shared__ unsigned sorted[BSTRIDE];                   // 8 KiB
    __shared__ __align__(8) unsigned short exs[BSTRIDE*4]; // 16 KiB: fp16 ex per head
    __shared__ int hist[BUCK];
    __shared__ int noff[BUCK + 1];
    __shared__ int cur[BUCK];
    __shared__ float er_s[BUCK * HEADS];                   // 1.75 KiB

    const int t = threadIdx.x;
    const int B = blockIdx.x;
    const int nodebase = B * BUCK;
    const unsigned* mybin = bin + (size_t)B * BSTRIDE;
    int cnt = gcur[B];
    if (cnt > BSTRIDE) cnt = BSTRIDE;

    if (t < BUCK) hist[t] = 0;
    if (t < BUCK * HEADS) {                // 448 < 512
        int g = nodebase * HEADS + t;
        er_s[t] = (g < N_NODES * HEADS) ? er[g] : 0.f;
    }
    __syncthreads();

    // fused stage + histogram: one vectorized global pass over this bucket's bin
    for (int i = t * 4; i < cnt; i += 2048) {          // i <= 2044, reads within BSTRIDE
        uint4 v = *(const uint4*)(mybin + i);
        *(uint4*)(raw + i) = v;
        atomicAdd(&hist[v.x >> 17], 1);
        if (i + 1 < cnt) atomicAdd(&hist[v.y >> 17], 1);
        if (i + 2 < cnt) atomicAdd(&hist[v.z >> 17], 1);
        if (i + 3 < cnt) atomicAdd(&hist[v.w >> 17], 1);
    }
    __syncthreads();

    // single-wave exclusive scan over 112 bins (2 per lane)
    if (t < 64) {
        int h0 = hist[t * 2], h1 = hist[t * 2 + 1];
        int acc = h0 + h1;
        int x = acc;
        #pragma unroll
        for (int o = 1; o < 64; o <<= 1) {
            int y = __shfl_up(x, o);
            if (t >= o) x += y;
        }
        int excl = x - acc;
        noff[t * 2] = excl;       cur[t * 2] = excl;
        noff[t * 2 + 1] = excl + h0; cur[t * 2 + 1] = excl + h0;
        if (t == 63) noff[BUCK] = x;
    }
    __syncthreads();

    // scatter src by dst-local + precompute per-edge ex (4 heads, fp16).
    // ~3.5 independent edges/thread -> el gathers fly in parallel.
    for (int i = t; i < cnt; i += 512) {
        unsigned p = raw[i];
        int d2 = (int)(p >> 17);
        int pos = atomicAdd(&cur[d2], 1);
        int sN = (int)(p & 0x1FFFF);
        float4 e4 = *(const float4*)(el + (size_t)sN * HEADS);
        float x0 = e4.x + er_s[d2 * HEADS + 0];
        float x1 = e4.y + er_s[d2 * HEADS + 1];
        float x2 = e4.z + er_s[d2 * HEADS + 2];
        float x3 = e4.w + er_s[d2 * HEADS + 3];
        x0 = x0 > 0.f ? x0 : NEG_SLOPE * x0;
        x1 = x1 > 0.f ? x1 : NEG_SLOPE * x1;
        x2 = x2 > 0.f ? x2 : NEG_SLOPE * x2;
        x3 = x3 > 0.f ? x3 : NEG_SLOPE * x3;
        unsigned short q0 = __builtin_bit_cast(unsigned short, (_Float16)__expf(x0));
        unsigned short q1 = __builtin_bit_cast(unsigned short, (_Float16)__expf(x1));
        unsigned short q2 = __builtin_bit_cast(unsigned short, (_Float16)__expf(x2));
        unsigned short q3 = __builtin_bit_cast(unsigned short, (_Float16)__expf(x3));
        sorted[pos] = (unsigned)sN;
        *(uint2*)(exs + pos * 4) =
            make_uint2((unsigned)q0 | ((unsigned)q1 << 16),
                       (unsigned)q2 | ((unsigned)q3 << 16));
    }
    __syncthreads();

    // aggregation: lane = j*8 + c; node-pair per wave: sel = j>>2 picks A/B, jj = j&3 edge slot
    const int wave = t >> 6, lane = t & 63;
    const int j = lane >> 3;
    const int c = lane & 7;
    const int h = c >> 1;
    const int jj = j & 3;
    const int sel = j >> 2;

    for (int p = wave; p < BUCK / 2; p += 8) {
        const int nl = p * 2 + sel;
        const int node = nodebase + nl;
        const int nlo = noff[nl], nhi = noff[nl + 1];

        float4 A0 = make_float4(0.f, 0.f, 0.f, 0.f);
        float4 A1 = make_float4(0.f, 0.f, 0.f, 0.f);
        float den = 0.f;
        for (int i = nlo + jj; i < nhi; i += 4) {
            int sN = (int)sorted[i];
            float ex = (float)__builtin_bit_cast(_Float16, exs[i * 4 + h]);
            uint4 v = *(const uint4*)(zb + (size_t)sN * HF + c * 8);
            den += ex;
            A0.x += ex * __uint_as_float(v.x << 16);
            A0.y += ex * __uint_as_float(v.x & 0xFFFF0000u);
            A0.z += ex * __uint_as_float(v.y << 16);
            A0.w += ex * __uint_as_float(v.y & 0xFFFF0000u);
            A1.x += ex * __uint_as_float(v.z << 16);
            A1.y += ex * __uint_as_float(v.z & 0xFFFF0000u);
            A1.z += ex * __uint_as_float(v.w << 16);
            A1.w += ex * __uint_as_float(v.w & 0xFFFF0000u);
        }
        // 2-level butterfly over jj (lane bits 3-4): masks 8, 16
        #pragma unroll
        for (int m = 8; m <= 16; m <<= 1) {
            A0.x += __shfl_xor(A0.x, m); A0.y += __shfl_xor(A0.y, m);
            A0.z += __shfl_xor(A0.z, m); A0.w += __shfl_xor(A0.w, m);
            A1.x += __shfl_xor(A1.x, m); A1.y += __shfl_xor(A1.y, m);
            A1.z += __shfl_xor(A1.z, m); A1.w += __shfl_xor(A1.w, m);
            den  += __shfl_xor(den,  m);
        }
        if (jj == 0 && node < N_NODES) {
            float4 b0 = *(const float4*)(bias + c * 8);
            float4 b1 = *(const float4*)(bias + c * 8 + 4);
            if (den > 0.f) {
                float inv = 1.f / den;
                b0.x += A0.x * inv; b0.y += A0.y * inv;
                b0.z += A0.z * inv; b0.w += A0.w * inv;
                b1.x += A1.x * inv; b1.y += A1.y * inv;
                b1.z += A1.z * inv; b1.w += A1.w * inv;
            }
            *(float4*)(out + (size_t)node * HF + c * 8) = b0;
            *(float4*)(out + (size_t)node * HF + c * 8 + 4) = b1;
        }
    }
}

extern "C" void kernel_launch(void* const* d_in, const int* in_sizes, int n_in,
                              void* d_out, int out_size, void* d_ws, size_t ws_size,
                              hipStream_t stream) {
    const float* feats  = (const float*)d_in[0];
    const float* W      = (const float*)d_in[1];
    const float* attn_l = (const float*)d_in[2];
    const float* attn_r = (const float*)d_in[3];
    const float* bias   = (const float*)d_in[4];
    const int*   src    = (const int*)d_in[5];
    const int*   dst    = (const int*)d_in[6];
    float* out = (float*)d_out;

    char* ws = (char*)d_ws;
    unsigned short* zb = (unsigned short*)ws;  ws += (size_t)N_NODES * HF * 2;
    float* el    = (float*)ws;                 ws += N_NODES * HEADS * 4;
    float* er    = (float*)ws;                 ws += N_NODES * HEADS * 4;
    unsigned short* Wfrag = (unsigned short*)ws; ws += 20 * 64 * 8 * 2;
    int*   gcur  = (int*)ws;                   ws += 1024 * 4;
    unsigned* bin = (unsigned*)ws;             ws += (size_t)NBUCK * BSTRIDE * 4;

    k_prep  <<<24,         256,  0, stream>>>(W, attn_l, attn_r, Wfrag, gcur);
    k_fused <<<NB_FUSED5,  512,  0, stream>>>(feats, Wfrag, zb, el, er, src, dst, gcur, bin);
    k3_sort <<<NBUCK,      512,  0, stream>>>(bin, gcur, el, er, zb, bias, out);
}